// Round 3
// baseline (362.598 us; speedup 1.0000x reference)
//
#include <hip/hip_runtime.h>

// Dice loss (hard, exclude background=class 0), B=2, C=8, S=128^3.
// pred: (B, C, 128,128,128) fp32 ; ref: (B, 1, 128,128,128) int32 ; out: scalar fp32.
// Single fused kernel: per-block counting + global accumulate + last-block finalize.

#define S_VOX (128 * 128 * 128)   // 2,097,152 voxels per (b, c) slice
#define S4    (S_VOX / 4)         // 524,288 float4 groups per slice
#define NC    8                   // channels
#define GX    512                 // blocks per batch
#define NBLK  (GX * 2)            // total blocks

// ws layout (int): [b*24 + t*8 + c] t:0=inter 1=pred 2=ref, c=0..7 ; [48]=done counter
#define WS_INTS 49

#define BYTE_MASK 0x00FF00FF00FF00FFULL

// Per-component: argmax over 8 channels (strict >, ascending = jnp.argmax
// first-max semantics), then one packed-byte increment per counter.
#define PROC_COMP(C)                                                     \
    {                                                                    \
        float bv = a0.C; int bi = 0;                                     \
        if (a1.C > bv) { bv = a1.C; bi = 1; }                            \
        if (a2.C > bv) { bv = a2.C; bi = 2; }                            \
        if (a3.C > bv) { bv = a3.C; bi = 3; }                            \
        if (a4.C > bv) { bv = a4.C; bi = 4; }                            \
        if (a5.C > bv) { bv = a5.C; bi = 5; }                            \
        if (a6.C > bv) { bv = a6.C; bi = 6; }                            \
        if (a7.C > bv) { bv = a7.C; bi = 7; }                            \
        const int rr = r.C;                                              \
        const unsigned long long pa = 1ULL << (bi * 8);                  \
        pcnt += pa;                                                      \
        rcnt += 1ULL << (rr * 8);                                        \
        icnt += (bi == rr) ? pa : 0ULL;                                  \
    }

__global__ __launch_bounds__(256) void dice_fused_kernel(
    const float4* __restrict__ pred4, const int4* __restrict__ ref4,
    int* __restrict__ ws, float* __restrict__ out)
{
    const int b = blockIdx.y;
    unsigned long long icnt = 0, pcnt = 0, rcnt = 0;   // 8 byte-lanes = 8 classes

    const int tid      = blockIdx.x * blockDim.x + threadIdx.x;
    const int nthreads = GX * 256;                     // per-batch threads -> 4 iters, 16 vox/thread
    const long long predBase = (long long)b * NC * S4;
    const long long refBase  = (long long)b * S4;

    for (int g = tid; g < S4; g += nthreads) {
        const float4 a0 = pred4[predBase + (long long)0 * S4 + g];
        const float4 a1 = pred4[predBase + (long long)1 * S4 + g];
        const float4 a2 = pred4[predBase + (long long)2 * S4 + g];
        const float4 a3 = pred4[predBase + (long long)3 * S4 + g];
        const float4 a4 = pred4[predBase + (long long)4 * S4 + g];
        const float4 a5 = pred4[predBase + (long long)5 * S4 + g];
        const float4 a6 = pred4[predBase + (long long)6 * S4 + g];
        const float4 a7 = pred4[predBase + (long long)7 * S4 + g];
        const int4   r  = ref4[refBase + g];
        PROC_COMP(x)
        PROC_COMP(y)
        PROC_COMP(z)
        PROC_COMP(w)
    }

    // Split packed bytes into 16-bit lanes (even classes in lo16, odd in hi16).
    unsigned w[12];
    {
        const unsigned long long li = icnt & BYTE_MASK, hi = (icnt >> 8) & BYTE_MASK;
        const unsigned long long lp = pcnt & BYTE_MASK, hp = (pcnt >> 8) & BYTE_MASK;
        const unsigned long long lr = rcnt & BYTE_MASK, hr = (rcnt >> 8) & BYTE_MASK;
        w[0] = (unsigned)li; w[1] = (unsigned)(li >> 32); w[2]  = (unsigned)hi; w[3]  = (unsigned)(hi >> 32);
        w[4] = (unsigned)lp; w[5] = (unsigned)(lp >> 32); w[6]  = (unsigned)hp; w[7]  = (unsigned)(hp >> 32);
        w[8] = (unsigned)lr; w[9] = (unsigned)(lr >> 32); w[10] = (unsigned)hr; w[11] = (unsigned)(hr >> 32);
    }

    // Wave reduction: 16-bit lane sums <= 64 lanes * 16 vox = 1024, no overflow.
#pragma unroll
    for (int j = 0; j < 12; ++j) {
#pragma unroll
        for (int off = 32; off > 0; off >>= 1)
            w[j] += __shfl_down(w[j], off, 64);
    }

    __shared__ unsigned sh[12];
    if (threadIdx.x < 12) sh[threadIdx.x] = 0;
    __syncthreads();
    if ((threadIdx.x & 63) == 0) {                     // block sums <= 4096, no overflow
#pragma unroll
        for (int j = 0; j < 12; ++j) atomicAdd(&sh[j], w[j]);
    }
    __syncthreads();

    if (threadIdx.x < 12) {
        const int j = threadIdx.x;
        const int t = j >> 2;                          // 0=inter 1=pred 2=ref
        const int c0tab[4] = {0, 4, 1, 5};
        const int c0 = c0tab[j & 3];                   // classes (c0, c0+2) in (lo16, hi16)
        const unsigned v = sh[j];
        atomicAdd(&ws[b * 24 + t * 8 + c0],     (int)(v & 0xFFFFu));
        atomicAdd(&ws[b * 24 + t * 8 + c0 + 2], (int)(v >> 16));
    }

    // ---- last-block finalize ----
    __threadfence();                                   // make our atomics visible device-wide
    __shared__ int amLast;
    if (threadIdx.x == 0) {
        const unsigned old = atomicAdd((unsigned*)&ws[48], 1u);
        amLast = (old == NBLK - 1) ? 1 : 0;
    }
    __syncthreads();
    if (amLast) {
        __shared__ int vals[48];
        if (threadIdx.x < 48)
            vals[threadIdx.x] = atomicAdd(&ws[threadIdx.x], 0);   // device-scope read
        __syncthreads();
        if (threadIdx.x == 0) {
            float total = 0.0f;
#pragma unroll
            for (int bb = 0; bb < 2; ++bb) {
                const int* v = vals + bb * 24;
                float sumd = 0.0f, sumw = 0.0f;
#pragma unroll
                for (int c = 1; c < NC; ++c) {
                    const int I = v[0 * 8 + c];
                    const int P = v[1 * 8 + c];
                    const int R = v[2 * 8 + c];
                    if (R > 0) {
                        sumw += 1.0f;
                        sumd += 2.0f * (float)I / (float)(P + R);
                    }
                }
                total += sumd / sumw;                  // matches reference (NaN if no fg)
            }
            out[0] = 0.5f * total;
        }
    }
}

extern "C" void kernel_launch(void* const* d_in, const int* in_sizes, int n_in,
                              void* d_out, int out_size, void* d_ws, size_t ws_size,
                              hipStream_t stream) {
    const float* pred = (const float*)d_in[0];
    const int*   ref  = (const int*)d_in[1];
    float*       out  = (float*)d_out;
    int*         ws   = (int*)d_ws;

    // ws is re-poisoned to 0xAA before every timed launch -> zero the 49 ints we use.
    hipMemsetAsync(ws, 0, WS_INTS * sizeof(int), stream);

    dim3 grid(GX, 2, 1);
    dim3 block(256, 1, 1);
    dice_fused_kernel<<<grid, block, 0, stream>>>(
        (const float4*)pred, (const int4*)ref, ws, out);
}

// Round 4
// 333.643 us; speedup vs baseline: 1.0868x; 1.0868x over previous
//
#include <hip/hip_runtime.h>

// Dice loss (hard, exclude background=class 0), B=2, C=8, S=128^3.
// pred: (B, C, 128,128,128) fp32 ; ref: (B, 1, 128,128,128) int32 ; out: scalar fp32.
//
// R4 probe: R2 two-kernel structure, but count kernel launched 4x (no memset
// between). Dice is invariant to uniform scaling of (I,P,R), so result is
// unchanged; total-dur delta vs R2 measures the count kernel's duration.

#define S_VOX (128 * 128 * 128)   // 2,097,152 voxels per (b, c) slice
#define S4    (S_VOX / 4)         // 524,288 float4 groups per slice
#define NC    8                   // channels
#define GX    512                 // blocks per batch

// ws layout (int): [b*24 + t*8 + c], t: 0=inter 1=pred 2=ref, c=class 0..7
#define WS_INTS (2 * 3 * NC)

#define BYTE_MASK 0x00FF00FF00FF00FFULL

// Per-component: argmax over 8 channels (strict >, ascending order = jnp.argmax
// first-max semantics), then one packed-byte increment per counter.
#define PROC_COMP(C)                                                     \
    {                                                                    \
        float bv = a0.C; int bi = 0;                                     \
        if (a1.C > bv) { bv = a1.C; bi = 1; }                            \
        if (a2.C > bv) { bv = a2.C; bi = 2; }                            \
        if (a3.C > bv) { bv = a3.C; bi = 3; }                            \
        if (a4.C > bv) { bv = a4.C; bi = 4; }                            \
        if (a5.C > bv) { bv = a5.C; bi = 5; }                            \
        if (a6.C > bv) { bv = a6.C; bi = 6; }                            \
        if (a7.C > bv) { bv = a7.C; bi = 7; }                            \
        const int rr = r.C;                                              \
        const unsigned long long pa = 1ULL << (bi * 8);                  \
        pcnt += pa;                                                      \
        rcnt += 1ULL << (rr * 8);                                        \
        icnt += (bi == rr) ? pa : 0ULL;                                  \
    }

__global__ __launch_bounds__(256) void dice_count_kernel(
    const float4* __restrict__ pred4, const int4* __restrict__ ref4,
    int* __restrict__ ws)
{
    const int b = blockIdx.y;
    unsigned long long icnt = 0, pcnt = 0, rcnt = 0;   // 8 byte-lanes = 8 classes

    const int tid      = blockIdx.x * blockDim.x + threadIdx.x;
    const int nthreads = GX * 256;                     // 4 iters, 16 vox/thread
    const long long predBase = (long long)b * NC * S4;
    const long long refBase  = (long long)b * S4;

    for (int g = tid; g < S4; g += nthreads) {
        const float4 a0 = pred4[predBase + (long long)0 * S4 + g];
        const float4 a1 = pred4[predBase + (long long)1 * S4 + g];
        const float4 a2 = pred4[predBase + (long long)2 * S4 + g];
        const float4 a3 = pred4[predBase + (long long)3 * S4 + g];
        const float4 a4 = pred4[predBase + (long long)4 * S4 + g];
        const float4 a5 = pred4[predBase + (long long)5 * S4 + g];
        const float4 a6 = pred4[predBase + (long long)6 * S4 + g];
        const float4 a7 = pred4[predBase + (long long)7 * S4 + g];
        const int4   r  = ref4[refBase + g];
        PROC_COMP(x)
        PROC_COMP(y)
        PROC_COMP(z)
        PROC_COMP(w)
    }

    // Split packed bytes into 16-bit lanes (even classes in lo16, odd in hi16).
    unsigned w[12];
    {
        const unsigned long long li = icnt & BYTE_MASK, hi = (icnt >> 8) & BYTE_MASK;
        const unsigned long long lp = pcnt & BYTE_MASK, hp = (pcnt >> 8) & BYTE_MASK;
        const unsigned long long lr = rcnt & BYTE_MASK, hr = (rcnt >> 8) & BYTE_MASK;
        w[0] = (unsigned)li; w[1] = (unsigned)(li >> 32); w[2]  = (unsigned)hi; w[3]  = (unsigned)(hi >> 32);
        w[4] = (unsigned)lp; w[5] = (unsigned)(lp >> 32); w[6]  = (unsigned)hp; w[7]  = (unsigned)(hp >> 32);
        w[8] = (unsigned)lr; w[9] = (unsigned)(lr >> 32); w[10] = (unsigned)hr; w[11] = (unsigned)(hr >> 32);
    }

    // Wave reduction: 16-bit lane sums <= 64 lanes * 16 vox = 1024, no overflow.
#pragma unroll
    for (int j = 0; j < 12; ++j) {
#pragma unroll
        for (int off = 32; off > 0; off >>= 1)
            w[j] += __shfl_down(w[j], off, 64);
    }

    __shared__ unsigned sh[12];
    if (threadIdx.x < 12) sh[threadIdx.x] = 0;
    __syncthreads();
    if ((threadIdx.x & 63) == 0) {                     // block sums <= 4096, no overflow
#pragma unroll
        for (int j = 0; j < 12; ++j) atomicAdd(&sh[j], w[j]);
    }
    __syncthreads();

    if (threadIdx.x < 12) {
        const int j = threadIdx.x;
        const int t = j >> 2;                          // 0=inter 1=pred 2=ref
        const int c0tab[4] = {0, 4, 1, 5};
        const int c0 = c0tab[j & 3];                   // classes (c0, c0+2) in (lo16, hi16)
        const unsigned v = sh[j];
        atomicAdd(&ws[b * 24 + t * 8 + c0],     (int)(v & 0xFFFFu));
        atomicAdd(&ws[b * 24 + t * 8 + c0 + 2], (int)(v >> 16));
    }
}

__global__ void dice_finalize_kernel(const int* __restrict__ ws,
                                     float* __restrict__ out)
{
    if (blockIdx.x == 0 && threadIdx.x == 0) {
        float total = 0.0f;
#pragma unroll
        for (int b = 0; b < 2; ++b) {
            const int* w = ws + b * 24;
            float sumd = 0.0f, sumw = 0.0f;
#pragma unroll
            for (int c = 1; c < NC; ++c) {
                const int I = w[0 * 8 + c];
                const int P = w[1 * 8 + c];
                const int R = w[2 * 8 + c];
                if (R > 0) {
                    sumw += 1.0f;
                    // counts are 4x true values; dice = 2*(4I)/(4P+4R) = 2I/(P+R)
                    sumd += 2.0f * (float)I / (float)(P + R);
                }
            }
            total += sumd / sumw;   // matches reference (NaN if no fg classes)
        }
        out[0] = 0.5f * total;
    }
}

extern "C" void kernel_launch(void* const* d_in, const int* in_sizes, int n_in,
                              void* d_out, int out_size, void* d_ws, size_t ws_size,
                              hipStream_t stream) {
    const float* pred = (const float*)d_in[0];
    const int*   ref  = (const int*)d_in[1];
    float*       out  = (float*)d_out;
    int*         ws   = (int*)d_ws;

    // ws is re-poisoned to 0xAA before every timed launch -> zero the ints we use.
    hipMemsetAsync(ws, 0, WS_INTS * sizeof(int), stream);

    dim3 grid(GX, 2, 1);
    dim3 block(256, 1, 1);
    // PROBE: 4 identical count launches. Dice is scale-invariant in (I,P,R),
    // so the final value is unchanged; dur delta vs single launch = 3x count dur.
    for (int rep = 0; rep < 4; ++rep) {
        dice_count_kernel<<<grid, block, 0, stream>>>(
            (const float4*)pred, (const int4*)ref, ws);
    }
    dice_finalize_kernel<<<1, 64, 0, stream>>>(ws, out);
}

// Round 5
// 226.317 us; speedup vs baseline: 1.6022x; 1.4742x over previous
//
#include <hip/hip_runtime.h>

// Dice loss (hard, exclude background=class 0), B=2, C=8, S=128^3.
// pred: (B, C, 128,128,128) fp32 ; ref: (B, 1, 128,128,128) int32 ; out: scalar fp32.
// R5: R2 two-kernel structure, GX=1024 (32 waves/CU, max occupancy) for MLP.

#define S_VOX (128 * 128 * 128)   // 2,097,152 voxels per (b, c) slice
#define S4    (S_VOX / 4)         // 524,288 float4 groups per slice
#define NC    8                   // channels
#define GX    1024                // blocks per batch -> 2048 blocks, 8/CU, 32 waves/CU

// ws layout (int): [b*24 + t*8 + c], t: 0=inter 1=pred 2=ref, c=class 0..7
#define WS_INTS (2 * 3 * NC)

#define BYTE_MASK 0x00FF00FF00FF00FFULL

// Per-component: argmax over 8 channels (strict >, ascending order = jnp.argmax
// first-max semantics), then one packed-byte increment per counter.
// Per-thread voxel count = 8 -> byte counters can't overflow.
#define PROC_COMP(C)                                                     \
    {                                                                    \
        float bv = a0.C; int bi = 0;                                     \
        if (a1.C > bv) { bv = a1.C; bi = 1; }                            \
        if (a2.C > bv) { bv = a2.C; bi = 2; }                            \
        if (a3.C > bv) { bv = a3.C; bi = 3; }                            \
        if (a4.C > bv) { bv = a4.C; bi = 4; }                            \
        if (a5.C > bv) { bv = a5.C; bi = 5; }                            \
        if (a6.C > bv) { bv = a6.C; bi = 6; }                            \
        if (a7.C > bv) { bv = a7.C; bi = 7; }                            \
        const int rr = r.C;                                              \
        const unsigned long long pa = 1ULL << (bi * 8);                  \
        pcnt += pa;                                                      \
        rcnt += 1ULL << (rr * 8);                                        \
        icnt += (bi == rr) ? pa : 0ULL;                                  \
    }

__global__ __launch_bounds__(256) void dice_count_kernel(
    const float4* __restrict__ pred4, const int4* __restrict__ ref4,
    int* __restrict__ ws)
{
    const int b = blockIdx.y;
    unsigned long long icnt = 0, pcnt = 0, rcnt = 0;   // 8 byte-lanes = 8 classes

    const int tid      = blockIdx.x * blockDim.x + threadIdx.x;
    const int nthreads = GX * 256;                     // 262144 -> exactly 2 iters
    const long long predBase = (long long)b * NC * S4;
    const long long refBase  = (long long)b * S4;

#pragma unroll 2
    for (int g = tid; g < S4; g += nthreads) {
        const float4 a0 = pred4[predBase + (long long)0 * S4 + g];
        const float4 a1 = pred4[predBase + (long long)1 * S4 + g];
        const float4 a2 = pred4[predBase + (long long)2 * S4 + g];
        const float4 a3 = pred4[predBase + (long long)3 * S4 + g];
        const float4 a4 = pred4[predBase + (long long)4 * S4 + g];
        const float4 a5 = pred4[predBase + (long long)5 * S4 + g];
        const float4 a6 = pred4[predBase + (long long)6 * S4 + g];
        const float4 a7 = pred4[predBase + (long long)7 * S4 + g];
        const int4   r  = ref4[refBase + g];
        PROC_COMP(x)
        PROC_COMP(y)
        PROC_COMP(z)
        PROC_COMP(w)
    }

    // Split packed bytes into 16-bit lanes (even classes in lo16, odd in hi16).
    unsigned w[12];
    {
        const unsigned long long li = icnt & BYTE_MASK, hi = (icnt >> 8) & BYTE_MASK;
        const unsigned long long lp = pcnt & BYTE_MASK, hp = (pcnt >> 8) & BYTE_MASK;
        const unsigned long long lr = rcnt & BYTE_MASK, hr = (rcnt >> 8) & BYTE_MASK;
        w[0] = (unsigned)li; w[1] = (unsigned)(li >> 32); w[2]  = (unsigned)hi; w[3]  = (unsigned)(hi >> 32);
        w[4] = (unsigned)lp; w[5] = (unsigned)(lp >> 32); w[6]  = (unsigned)hp; w[7]  = (unsigned)(hp >> 32);
        w[8] = (unsigned)lr; w[9] = (unsigned)(lr >> 32); w[10] = (unsigned)hr; w[11] = (unsigned)(hr >> 32);
    }

    // Wave reduction: 16-bit lane sums <= 64 lanes * 8 vox = 512, no overflow.
#pragma unroll
    for (int j = 0; j < 12; ++j) {
#pragma unroll
        for (int off = 32; off > 0; off >>= 1)
            w[j] += __shfl_down(w[j], off, 64);
    }

    __shared__ unsigned sh[12];
    if (threadIdx.x < 12) sh[threadIdx.x] = 0;
    __syncthreads();
    if ((threadIdx.x & 63) == 0) {                     // block sums <= 2048, no overflow
#pragma unroll
        for (int j = 0; j < 12; ++j) atomicAdd(&sh[j], w[j]);
    }
    __syncthreads();

    if (threadIdx.x < 12) {
        const int j = threadIdx.x;
        const int t = j >> 2;                          // 0=inter 1=pred 2=ref
        const int c0tab[4] = {0, 4, 1, 5};
        const int c0 = c0tab[j & 3];                   // classes (c0, c0+2) in (lo16, hi16)
        const unsigned v = sh[j];
        atomicAdd(&ws[b * 24 + t * 8 + c0],     (int)(v & 0xFFFFu));
        atomicAdd(&ws[b * 24 + t * 8 + c0 + 2], (int)(v >> 16));
    }
}

__global__ void dice_finalize_kernel(const int* __restrict__ ws,
                                     float* __restrict__ out)
{
    if (blockIdx.x == 0 && threadIdx.x == 0) {
        float total = 0.0f;
#pragma unroll
        for (int b = 0; b < 2; ++b) {
            const int* w = ws + b * 24;
            float sumd = 0.0f, sumw = 0.0f;
#pragma unroll
            for (int c = 1; c < NC; ++c) {
                const int I = w[0 * 8 + c];
                const int P = w[1 * 8 + c];
                const int R = w[2 * 8 + c];
                if (R > 0) {
                    sumw += 1.0f;
                    sumd += 2.0f * (float)I / (float)(P + R);
                }
            }
            total += sumd / sumw;   // matches reference (NaN if no fg classes)
        }
        out[0] = 0.5f * total;
    }
}

extern "C" void kernel_launch(void* const* d_in, const int* in_sizes, int n_in,
                              void* d_out, int out_size, void* d_ws, size_t ws_size,
                              hipStream_t stream) {
    const float* pred = (const float*)d_in[0];
    const int*   ref  = (const int*)d_in[1];
    float*       out  = (float*)d_out;
    int*         ws   = (int*)d_ws;

    // ws is re-poisoned to 0xAA before every timed launch -> zero the ints we use.
    hipMemsetAsync(ws, 0, WS_INTS * sizeof(int), stream);

    dim3 grid(GX, 2, 1);
    dim3 block(256, 1, 1);
    dice_count_kernel<<<grid, block, 0, stream>>>(
        (const float4*)pred, (const int4*)ref, ws);
    dice_finalize_kernel<<<1, 64, 0, stream>>>(ws, out);
}

// Round 6
// 213.165 us; speedup vs baseline: 1.7010x; 1.0617x over previous
//
#include <hip/hip_runtime.h>

// Dice loss (hard, exclude background=class 0), B=2, C=8, S=128^3.
// pred: (B, C, 128,128,128) fp32 ; ref: (B, 1, 128,128,128) int32 ; out: scalar fp32.
// R6: GX=512 (R2 config) + depth-2 software pipeline (prefetch next group's 9
// loads while computing current). __launch_bounds__(256,4) -> VGPR cap 128 so
// the 2x36-VGPR payload stays resident instead of the compiler serializing.

#define S_VOX (128 * 128 * 128)   // 2,097,152 voxels per (b, c) slice
#define S4    (S_VOX / 4)         // 524,288 float4 groups per slice
#define NC    8                   // channels
#define GX    512                 // blocks per batch; 1024 blocks, 16 waves/CU
#define NTH   (GX * 256)          // 131072 threads per batch; S4 = 4*NTH exactly

// ws layout (int): [b*24 + t*8 + c], t: 0=inter 1=pred 2=ref, c=class 0..7
#define WS_INTS (2 * 3 * NC)

#define BYTE_MASK 0x00FF00FF00FF00FFULL

// Per-component: argmax over 8 channels (strict >, ascending order = jnp.argmax
// first-max semantics), then one packed-byte increment per counter.
// 16 voxels/thread -> byte counters can't overflow.
#define PROC_COMP(C)                                                     \
    {                                                                    \
        float bv = a0.C; int bi = 0;                                     \
        if (a1.C > bv) { bv = a1.C; bi = 1; }                            \
        if (a2.C > bv) { bv = a2.C; bi = 2; }                            \
        if (a3.C > bv) { bv = a3.C; bi = 3; }                            \
        if (a4.C > bv) { bv = a4.C; bi = 4; }                            \
        if (a5.C > bv) { bv = a5.C; bi = 5; }                            \
        if (a6.C > bv) { bv = a6.C; bi = 6; }                            \
        if (a7.C > bv) { bv = a7.C; bi = 7; }                            \
        const int rr = r.C;                                              \
        const unsigned long long pa = 1ULL << (bi * 8);                  \
        pcnt += pa;                                                      \
        rcnt += 1ULL << (rr * 8);                                        \
        icnt += (bi == rr) ? pa : 0ULL;                                  \
    }

__global__ __launch_bounds__(256, 4) void dice_count_kernel(
    const float4* __restrict__ pred4, const int4* __restrict__ ref4,
    int* __restrict__ ws)
{
    const int b = blockIdx.y;
    unsigned long long icnt = 0, pcnt = 0, rcnt = 0;   // 8 byte-lanes = 8 classes

    const int tid = blockIdx.x * 256 + threadIdx.x;
    const float4* __restrict__ pb = pred4 + (long long)b * NC * S4;
    const int4*   __restrict__ rb = ref4  + (long long)b * S4;

    // Current-group payload (36 VGPRs) + next-group payload (36 VGPRs).
    float4 a0, a1, a2, a3, a4, a5, a6, a7; int4 r;
    float4 n0, n1, n2, n3, n4, n5, n6, n7; int4 nr;

    int g = tid;
    a0 = pb[0 * S4 + g]; a1 = pb[1 * S4 + g];
    a2 = pb[2 * S4 + g]; a3 = pb[3 * S4 + g];
    a4 = pb[4 * S4 + g]; a5 = pb[5 * S4 + g];
    a6 = pb[6 * S4 + g]; a7 = pb[7 * S4 + g];
    r  = rb[g];

#pragma unroll
    for (int k = 0; k < 4; ++k) {
        const int gn = g + NTH;
        if (k < 3) {
            // Prefetch group k+1 before consuming group k: these 9 loads
            // overlap the ~1600-cycle argmax dependency chain below.
            n0 = pb[0 * S4 + gn]; n1 = pb[1 * S4 + gn];
            n2 = pb[2 * S4 + gn]; n3 = pb[3 * S4 + gn];
            n4 = pb[4 * S4 + gn]; n5 = pb[5 * S4 + gn];
            n6 = pb[6 * S4 + gn]; n7 = pb[7 * S4 + gn];
            nr = rb[gn];
        }
        PROC_COMP(x)
        PROC_COMP(y)
        PROC_COMP(z)
        PROC_COMP(w)
        if (k < 3) {
            a0 = n0; a1 = n1; a2 = n2; a3 = n3;
            a4 = n4; a5 = n5; a6 = n6; a7 = n7;
            r = nr;
        }
        g = gn;
    }

    // Split packed bytes into 16-bit lanes (even classes in lo16, odd in hi16).
    unsigned w[12];
    {
        const unsigned long long li = icnt & BYTE_MASK, hi = (icnt >> 8) & BYTE_MASK;
        const unsigned long long lp = pcnt & BYTE_MASK, hp = (pcnt >> 8) & BYTE_MASK;
        const unsigned long long lr = rcnt & BYTE_MASK, hr = (rcnt >> 8) & BYTE_MASK;
        w[0] = (unsigned)li; w[1] = (unsigned)(li >> 32); w[2]  = (unsigned)hi; w[3]  = (unsigned)(hi >> 32);
        w[4] = (unsigned)lp; w[5] = (unsigned)(lp >> 32); w[6]  = (unsigned)hp; w[7]  = (unsigned)(hp >> 32);
        w[8] = (unsigned)lr; w[9] = (unsigned)(lr >> 32); w[10] = (unsigned)hr; w[11] = (unsigned)(hr >> 32);
    }

    // Wave reduction: 16-bit lane sums <= 64 lanes * 16 vox = 1024, no overflow.
#pragma unroll
    for (int j = 0; j < 12; ++j) {
#pragma unroll
        for (int off = 32; off > 0; off >>= 1)
            w[j] += __shfl_down(w[j], off, 64);
    }

    __shared__ unsigned sh[12];
    if (threadIdx.x < 12) sh[threadIdx.x] = 0;
    __syncthreads();
    if ((threadIdx.x & 63) == 0) {                     // block sums <= 4096, no overflow
#pragma unroll
        for (int j = 0; j < 12; ++j) atomicAdd(&sh[j], w[j]);
    }
    __syncthreads();

    if (threadIdx.x < 12) {
        const int j = threadIdx.x;
        const int t = j >> 2;                          // 0=inter 1=pred 2=ref
        const int c0tab[4] = {0, 4, 1, 5};
        const int c0 = c0tab[j & 3];                   // classes (c0, c0+2) in (lo16, hi16)
        const unsigned v = sh[j];
        atomicAdd(&ws[b * 24 + t * 8 + c0],     (int)(v & 0xFFFFu));
        atomicAdd(&ws[b * 24 + t * 8 + c0 + 2], (int)(v >> 16));
    }
}

__global__ void dice_finalize_kernel(const int* __restrict__ ws,
                                     float* __restrict__ out)
{
    if (blockIdx.x == 0 && threadIdx.x == 0) {
        float total = 0.0f;
#pragma unroll
        for (int b = 0; b < 2; ++b) {
            const int* w = ws + b * 24;
            float sumd = 0.0f, sumw = 0.0f;
#pragma unroll
            for (int c = 1; c < NC; ++c) {
                const int I = w[0 * 8 + c];
                const int P = w[1 * 8 + c];
                const int R = w[2 * 8 + c];
                if (R > 0) {
                    sumw += 1.0f;
                    sumd += 2.0f * (float)I / (float)(P + R);
                }
            }
            total += sumd / sumw;   // matches reference (NaN if no fg classes)
        }
        out[0] = 0.5f * total;
    }
}

extern "C" void kernel_launch(void* const* d_in, const int* in_sizes, int n_in,
                              void* d_out, int out_size, void* d_ws, size_t ws_size,
                              hipStream_t stream) {
    const float* pred = (const float*)d_in[0];
    const int*   ref  = (const int*)d_in[1];
    float*       out  = (float*)d_out;
    int*         ws   = (int*)d_ws;

    // ws is re-poisoned to 0xAA before every timed launch -> zero the ints we use.
    hipMemsetAsync(ws, 0, WS_INTS * sizeof(int), stream);

    dim3 grid(GX, 2, 1);
    dim3 block(256, 1, 1);
    dice_count_kernel<<<grid, block, 0, stream>>>(
        (const float4*)pred, (const int4*)ref, ws);
    dice_finalize_kernel<<<1, 64, 0, stream>>>(ws, out);
}